// Round 1
// baseline (165.700 us; speedup 1.0000x reference)
//
#include <hip/hip_runtime.h>

// Problem: x [B=64, C=512, H=28, W=28] f32, cc [B,H,W] bool mask.
// out[b, 0:512]   = (sum_{hw} x[b,c,hw]*m[b,hw] + x[b,c,0,0]) / max(cnt[b],1-if-zero)
// out[b, 512:1024]= max_{hw} x[b,c,hw]
// Memory-bound: 102.8 MB read, ~16 us at 6.3 TB/s.

#define HW 784          // 28*28
#define NC 512
#define NB 64

__global__ __launch_bounds__(256) void pool_model_kernel(
    const float* __restrict__ x,
    const void* __restrict__ cc,
    float* __restrict__ out)
{
    __shared__ float sm[HW];     // mask row as f32
    __shared__ float s_cnt;
    __shared__ int s_bad_int;    // nonzero -> not int32-encoded
    __shared__ int s_bad_flt;    // nonzero -> not float32-encoded

    const int b     = blockIdx.x >> 7;     // / 128
    const int chunk = blockIdx.x & 127;
    const int t     = threadIdx.x;

    if (t == 0) { s_bad_int = 0; s_bad_flt = 0; s_cnt = 0.0f; }
    __syncthreads();

    // ---- detect cc storage format ----
    // Read 196 ints at byte offset b*784 (in-bounds for uint8 [50176 B],
    // int32 [200704 B], and float32 [200704 B] encodings).
    //  int32 0/1:   every int in {0,1}
    //  float32 0/1: every int in {0x00000000, 0x3F800000}
    //  uint8 0/1:   packed 0/1 bytes -> fails both tests w.h.p.
    const int* cci = (const int*)cc;
    if (t < 196) {
        int v = cci[b * 196 + t];
        if (v & ~1) atomicOr(&s_bad_int, 1);
        if (v != 0 && v != 0x3F800000) atomicOr(&s_bad_flt, 1);
    }
    __syncthreads();

    // ---- stage mask row into LDS + count ----
    float local = 0.0f;
    if (s_bad_int == 0) {
        const int* row = cci + (size_t)b * HW;
        for (int i = t; i < HW; i += 256) {
            float mv = (float)row[i];
            sm[i] = mv; local += mv;
        }
    } else if (s_bad_flt == 0) {
        const float* row = (const float*)cc + (size_t)b * HW;
        for (int i = t; i < HW; i += 256) {
            float mv = row[i];
            sm[i] = mv; local += mv;
        }
    } else {
        const unsigned char* row = (const unsigned char*)cc + (size_t)b * HW;
        for (int i = t; i < HW; i += 256) {
            float mv = (float)row[i];
            sm[i] = mv; local += mv;
        }
    }
    atomicAdd(&s_cnt, local);
    __syncthreads();

    const float cnt   = s_cnt;
    const float denom = (cnt == 0.0f) ? 1.0f : cnt;

    // ---- per-wave c-row reduction ----
    const int wave = t >> 6;
    const int lane = t & 63;
    const int c    = chunk * 4 + wave;

    const float4* xr = (const float4*)(x + (size_t)(b * NC + c) * HW);
    float sum = 0.0f;
    float mx  = -INFINITY;
    // 784 floats = 196 float4; lanes stride the row (coalesced 1 KiB/iter)
    for (int v = lane; v < 196; v += 64) {
        float4 q  = xr[v];
        float4 m4 = *(const float4*)(sm + v * 4);
        sum += q.x * m4.x + q.y * m4.y + q.z * m4.z + q.w * m4.w;
        mx = fmaxf(mx, fmaxf(fmaxf(q.x, q.y), fmaxf(q.z, q.w)));
        if (v == 0) sum += q.x;   // the reference's + x[b,c,0,0] term
    }
    // wave64 butterfly-free down-reduction (6 steps)
    for (int off = 32; off > 0; off >>= 1) {
        sum += __shfl_down(sum, off);
        mx  = fmaxf(mx, __shfl_down(mx, off));
    }
    if (lane == 0) {
        out[(size_t)b * (2 * NC) + c]      = sum / denom;
        out[(size_t)b * (2 * NC) + NC + c] = mx;
    }
}

extern "C" void kernel_launch(void* const* d_in, const int* in_sizes, int n_in,
                              void* d_out, int out_size, void* d_ws, size_t ws_size,
                              hipStream_t stream) {
    const float* x  = (const float*)d_in[0];
    const void*  cc = d_in[1];
    float* out = (float*)d_out;
    // 64 batches x 128 chunks of 4 channels = 8192 blocks, 256 threads each
    pool_model_kernel<<<dim3(NB * 128), dim3(256), 0, stream>>>(x, cc, out);
}

// Round 2
// 155.560 us; speedup vs baseline: 1.0652x; 1.0652x over previous
//
#include <hip/hip_runtime.h>

// x [B=64, C=512, H=28, W=28] f32, cc [B,H,W] bool.
// out[b, 0:512]   = (masked_sum + x[b,c,0,0]) / max-ish(cnt)
// out[b, 512:1024]= global spatial max
//
// Two kernels:
//   1) mask_prep: per-batch block; detect cc encoding (int32/f32/uint8),
//      canonicalize mask to f32 in d_ws, write 1/denom[b].
//   2) pool_main: barrier-free; wave holds mask in registers, 4 channels/wave,
//      coalesced float4 x loads, shuffle reduction. 2048 blocks.

#define HW   784      // 28*28
#define NV4  196      // HW/4
#define NC   512
#define NB   64

__global__ __launch_bounds__(256) void mask_prep_kernel(
    const void* __restrict__ cc, float* __restrict__ mask_f,
    float* __restrict__ invd)
{
    __shared__ float s_cnt;
    __shared__ int s_bad_int, s_bad_flt;
    const int b = blockIdx.x;
    const int t = threadIdx.x;
    if (t == 0) { s_cnt = 0.0f; s_bad_int = 0; s_bad_flt = 0; }
    __syncthreads();

    // Detect encoding: read 196 ints at byte offset b*784 (in-bounds for
    // uint8 [50176 B], int32/f32 [200704 B]).
    const int* cci = (const int*)cc;
    if (t < NV4) {
        int v = cci[b * NV4 + t];
        if (v & ~1) atomicOr(&s_bad_int, 1);
        if (v != 0 && v != 0x3F800000) atomicOr(&s_bad_flt, 1);
    }
    __syncthreads();

    float local = 0.0f;
    if (s_bad_int == 0) {
        const int* row = cci + (size_t)b * HW;
        for (int i = t; i < HW; i += 256) {
            float mv = (float)row[i];
            mask_f[b * HW + i] = mv; local += mv;
        }
    } else if (s_bad_flt == 0) {
        const float* row = (const float*)cc + (size_t)b * HW;
        for (int i = t; i < HW; i += 256) {
            float mv = row[i];
            mask_f[b * HW + i] = mv; local += mv;
        }
    } else {
        const unsigned char* row = (const unsigned char*)cc + (size_t)b * HW;
        for (int i = t; i < HW; i += 256) {
            float mv = (float)row[i];
            mask_f[b * HW + i] = mv; local += mv;
        }
    }
    atomicAdd(&s_cnt, local);
    __syncthreads();
    if (t == 0) {
        float c = s_cnt;
        invd[b] = 1.0f / ((c == 0.0f) ? 1.0f : c);
    }
}

__device__ __forceinline__ float dot4(float4 a, float4 b) {
    return a.x * b.x + a.y * b.y + a.z * b.z + a.w * b.w;
}
__device__ __forceinline__ float max4(float4 a) {
    return fmaxf(fmaxf(a.x, a.y), fmaxf(a.z, a.w));
}

__global__ __launch_bounds__(256) void pool_main_kernel(
    const float* __restrict__ x, const float* __restrict__ mask_f,
    const float* __restrict__ invd, float* __restrict__ out)
{
    const int blk  = blockIdx.x;          // 2048 blocks
    const int b    = blk >> 5;
    const int grp  = blk & 31;
    const int t    = threadIdx.x;
    const int wave = t >> 6;
    const int lane = t & 63;
    const int c0   = grp * 16 + wave * 4; // 4 channels per wave

    // Mask in registers: lane covers float4s {lane, lane+64, lane+128, lane+192<4>}
    const float4* m4 = (const float4*)(mask_f + (size_t)b * HW);
    float4 m0 = m4[lane];
    float4 m1 = m4[lane + 64];
    float4 m2 = m4[lane + 128];
    float4 m3 = (lane < 4) ? m4[lane + 192] : make_float4(0.f, 0.f, 0.f, 0.f);
    const float inv = invd[b];

    float s[4], mx[4];
#pragma unroll
    for (int j = 0; j < 4; ++j) {
        const float4* xr = (const float4*)(x + (size_t)(b * NC + c0 + j) * HW);
        float4 q0 = xr[lane];
        float4 q1 = xr[lane + 64];
        float4 q2 = xr[lane + 128];
        float sum = dot4(q0, m0) + dot4(q1, m1) + dot4(q2, m2);
        float mm  = fmaxf(fmaxf(max4(q0), max4(q1)), max4(q2));
        if (lane < 4) {
            float4 q3 = xr[lane + 192];
            sum += dot4(q3, m3);
            mm = fmaxf(mm, max4(q3));
        }
        if (lane == 0) sum += q0.x;  // reference's + x[b,c,0,0]
        s[j] = sum; mx[j] = mm;
    }

#pragma unroll
    for (int j = 0; j < 4; ++j) {
        float sum = s[j], mm = mx[j];
        for (int off = 32; off > 0; off >>= 1) {
            sum += __shfl_down(sum, off);
            mm   = fmaxf(mm, __shfl_down(mm, off));
        }
        if (lane == 0) {
            const int c = c0 + j;
            out[(size_t)b * (2 * NC) + c]      = sum * inv;
            out[(size_t)b * (2 * NC) + NC + c] = mm;
        }
    }
}

extern "C" void kernel_launch(void* const* d_in, const int* in_sizes, int n_in,
                              void* d_out, int out_size, void* d_ws, size_t ws_size,
                              hipStream_t stream) {
    const float* x  = (const float*)d_in[0];
    const void*  cc = d_in[1];
    float* out    = (float*)d_out;
    float* mask_f = (float*)d_ws;                    // 64*784 floats = 200704 B
    float* invd   = (float*)d_ws + (size_t)NB * HW;  // 64 floats

    mask_prep_kernel<<<dim3(NB), dim3(256), 0, stream>>>(cc, mask_f, invd);
    pool_main_kernel<<<dim3(NB * 32), dim3(256), 0, stream>>>(x, mask_f, invd, out);
}

// Round 3
// 152.033 us; speedup vs baseline: 1.0899x; 1.0232x over previous
//
#include <hip/hip_runtime.h>

// x [B=64, C=512, H=28, W=28] f32, cc [B,H,W] bool.
// out[b, 0:512]    = (sum_hw x*m + x[b,c,0,0]) / (cnt==0 ? 1 : cnt)
// out[b, 512:1024] = max_hw x
//
// Single fused barrier-free kernel: each wave owns 4 channels of one batch,
// holds the full 784-elem mask row in registers, self-detects the cc
// encoding (int32 / f32 / uint8) via an always-in-bounds 196-int sample +
// wave votes, and folds the mask count into the shuffle reduction.

#define HW 784      // 28*28
#define NC 512
#define NB 64

__device__ __forceinline__ float dot4(float4 a, float4 b) {
    return a.x * b.x + a.y * b.y + a.z * b.z + a.w * b.w;
}
__device__ __forceinline__ float max4(float4 a) {
    return fmaxf(fmaxf(a.x, a.y), fmaxf(a.z, a.w));
}
__device__ __forceinline__ float sum4(float4 a) {
    return a.x + a.y + a.z + a.w;
}
__device__ __forceinline__ float4 unpack_u8(unsigned int u) {
    return make_float4((float)(u & 0xff), (float)((u >> 8) & 0xff),
                       (float)((u >> 16) & 0xff), (float)((u >> 24) & 0xff));
}

__global__ __launch_bounds__(256) void pool_fused_kernel(
    const float* __restrict__ x, const void* __restrict__ cc,
    float* __restrict__ out)
{
    const int blk  = blockIdx.x;      // 2048 blocks
    const int b    = blk >> 5;
    const int grp  = blk & 31;
    const int t    = threadIdx.x;
    const int wave = t >> 6;
    const int lane = t & 63;
    const int c0   = grp * 16 + wave * 4;

    // ---- encoding detection (wave-local, no barrier) ----
    // Sample 196 ints at byte offset b*784: in-bounds for uint8 (50176 B)
    // and int32/f32 (200704 B) encodings alike.
    int badInt = 0, badFlt = 0;
    {
        const int4* det = (const int4*)((const unsigned char*)cc + (size_t)b * HW);
        if (lane < 49) {
            int4 d = det[lane];
            badInt = (d.x | d.y | d.z | d.w) & ~1;
            badFlt = (d.x && d.x != 0x3F800000) || (d.y && d.y != 0x3F800000) ||
                     (d.z && d.z != 0x3F800000) || (d.w && d.w != 0x3F800000);
        }
    }
    const bool isInt = !__any(badInt != 0);
    const bool isFlt = !__any(badFlt);

    // ---- mask row -> registers (lane covers float4s lane, +64, +128, +192<4) ----
    float4 m0, m1, m2, m3 = make_float4(0.f, 0.f, 0.f, 0.f);
    if (isInt) {
        const int4* mi = (const int4*)cc + (size_t)b * 196;
        int4 a = mi[lane], e = mi[lane + 64], f = mi[lane + 128];
        m0 = make_float4((float)a.x, (float)a.y, (float)a.z, (float)a.w);
        m1 = make_float4((float)e.x, (float)e.y, (float)e.z, (float)e.w);
        m2 = make_float4((float)f.x, (float)f.y, (float)f.z, (float)f.w);
        if (lane < 4) {
            int4 g = mi[lane + 192];
            m3 = make_float4((float)g.x, (float)g.y, (float)g.z, (float)g.w);
        }
    } else if (isFlt) {
        const float4* mf = (const float4*)cc + (size_t)b * 196;
        m0 = mf[lane]; m1 = mf[lane + 64]; m2 = mf[lane + 128];
        if (lane < 4) m3 = mf[lane + 192];
    } else {
        const unsigned int* row =
            (const unsigned int*)((const unsigned char*)cc + (size_t)b * HW);
        m0 = unpack_u8(row[lane]);
        m1 = unpack_u8(row[lane + 64]);
        m2 = unpack_u8(row[lane + 128]);
        if (lane < 4) m3 = unpack_u8(row[lane + 192]);
    }

    float mc = sum4(m0) + sum4(m1) + sum4(m2) + sum4(m3);  // partial mask count

    // ---- 4 channels per wave: coalesced float4 stream of x ----
    float s[4], mx[4];
#pragma unroll
    for (int j = 0; j < 4; ++j) {
        const float4* xr = (const float4*)(x + (size_t)(b * NC + c0 + j) * HW);
        float4 q0 = xr[lane];
        float4 q1 = xr[lane + 64];
        float4 q2 = xr[lane + 128];
        float sum = dot4(q0, m0) + dot4(q1, m1) + dot4(q2, m2);
        float mm  = fmaxf(fmaxf(max4(q0), max4(q1)), max4(q2));
        if (lane < 4) {
            float4 q3 = xr[lane + 192];
            sum += dot4(q3, m3);
            mm = fmaxf(mm, max4(q3));
        }
        if (lane == 0) sum += q0.x;   // reference's + x[b,c,0,0] term
        s[j] = sum; mx[j] = mm;
    }

    // ---- wave reductions: 4 sums, 4 maxes, 1 count ----
    for (int off = 32; off > 0; off >>= 1) {
        mc += __shfl_down(mc, off);
#pragma unroll
        for (int j = 0; j < 4; ++j) {
            s[j] += __shfl_down(s[j], off);
            mx[j] = fmaxf(mx[j], __shfl_down(mx[j], off));
        }
    }

    if (lane == 0) {
        const float inv = 1.0f / ((mc == 0.0f) ? 1.0f : mc);
#pragma unroll
        for (int j = 0; j < 4; ++j) {
            const int c = c0 + j;
            out[(size_t)b * (2 * NC) + c]      = s[j] * inv;
            out[(size_t)b * (2 * NC) + NC + c] = mx[j];
        }
    }
}

extern "C" void kernel_launch(void* const* d_in, const int* in_sizes, int n_in,
                              void* d_out, int out_size, void* d_ws, size_t ws_size,
                              hipStream_t stream) {
    const float* x  = (const float*)d_in[0];
    const void*  cc = d_in[1];
    float* out = (float*)d_out;
    pool_fused_kernel<<<dim3(NB * 32), dim3(256), 0, stream>>>(x, cc, out);
}

// Round 5
// 143.483 us; speedup vs baseline: 1.1548x; 1.0596x over previous
//
#include <hip/hip_runtime.h>

// x [B=64, C=512, H=28, W=28] f32, cc [B,H,W] bool.
// out[b, 0:512]    = (sum_hw x*m + x[b,c,0,0]) / (cnt==0 ? 1 : cnt)
// out[b, 512:1024] = max_hw x
//
// Single fused barrier-free kernel. Each wave owns 8 channels of one batch:
// holds the 784-elem mask row in registers, self-detects cc encoding
// (int32 / f32 / uint8) via in-bounds sample + wave votes, streams x with
// nontemporal float4 loads (read-once; don't thrash L2), folds the mask
// count into the shuffle reduction. 1024 blocks = 4 blocks/CU, uniform work.

#define HW 784      // 28*28
#define NC 512
#define NB 64

typedef float  vfloat4 __attribute__((ext_vector_type(4)));

__device__ __forceinline__ float dot4(float4 a, float4 b) {
    return a.x * b.x + a.y * b.y + a.z * b.z + a.w * b.w;
}
__device__ __forceinline__ float max4(float4 a) {
    return fmaxf(fmaxf(a.x, a.y), fmaxf(a.z, a.w));
}
__device__ __forceinline__ float sum4(float4 a) {
    return a.x + a.y + a.z + a.w;
}
__device__ __forceinline__ float4 unpack_u8(unsigned int u) {
    return make_float4((float)(u & 0xff), (float)((u >> 8) & 0xff),
                       (float)((u >> 16) & 0xff), (float)((u >> 24) & 0xff));
}
__device__ __forceinline__ float4 ntload4(const float4* p) {
    vfloat4 v = __builtin_nontemporal_load((const vfloat4*)p);
    return make_float4(v.x, v.y, v.z, v.w);
}

__global__ __launch_bounds__(256) void pool_fused_kernel(
    const float* __restrict__ x, const void* __restrict__ cc,
    float* __restrict__ out)
{
    const int blk  = blockIdx.x;      // 1024 blocks
    const int b    = blk >> 4;
    const int grp  = blk & 15;
    const int t    = threadIdx.x;
    const int wave = t >> 6;
    const int lane = t & 63;
    const int c0   = grp * 32 + wave * 8;   // 8 channels per wave

    // ---- encoding detection (wave-local, no barrier) ----
    // Sample 196 ints at byte offset b*784: in-bounds for uint8 (50176 B)
    // and int32/f32 (200704 B) encodings alike.
    int badInt = 0, badFlt = 0;
    {
        const int4* det = (const int4*)((const unsigned char*)cc + (size_t)b * HW);
        if (lane < 49) {
            int4 d = det[lane];
            badInt = (d.x | d.y | d.z | d.w) & ~1;
            badFlt = (d.x && d.x != 0x3F800000) || (d.y && d.y != 0x3F800000) ||
                     (d.z && d.z != 0x3F800000) || (d.w && d.w != 0x3F800000);
        }
    }
    const bool isInt = !__any(badInt != 0);
    const bool isFlt = !__any(badFlt);

    // ---- mask row -> registers (lane covers float4s lane, +64, +128, +192<4) ----
    float4 m0, m1, m2, m3 = make_float4(0.f, 0.f, 0.f, 0.f);
    if (isInt) {
        const int4* mi = (const int4*)cc + (size_t)b * 196;
        int4 a = mi[lane], e = mi[lane + 64], f = mi[lane + 128];
        m0 = make_float4((float)a.x, (float)a.y, (float)a.z, (float)a.w);
        m1 = make_float4((float)e.x, (float)e.y, (float)e.z, (float)e.w);
        m2 = make_float4((float)f.x, (float)f.y, (float)f.z, (float)f.w);
        if (lane < 4) {
            int4 g = mi[lane + 192];
            m3 = make_float4((float)g.x, (float)g.y, (float)g.z, (float)g.w);
        }
    } else if (isFlt) {
        const float4* mf = (const float4*)cc + (size_t)b * 196;
        m0 = mf[lane]; m1 = mf[lane + 64]; m2 = mf[lane + 128];
        if (lane < 4) m3 = mf[lane + 192];
    } else {
        const unsigned int* row =
            (const unsigned int*)((const unsigned char*)cc + (size_t)b * HW);
        m0 = unpack_u8(row[lane]);
        m1 = unpack_u8(row[lane + 64]);
        m2 = unpack_u8(row[lane + 128]);
        if (lane < 4) m3 = unpack_u8(row[lane + 192]);
    }

    float mc = sum4(m0) + sum4(m1) + sum4(m2) + sum4(m3);  // partial mask count

    // ---- 8 channels per wave: coalesced nontemporal float4 stream of x ----
    float s[8], mx[8];
#pragma unroll
    for (int j = 0; j < 8; ++j) {
        const float4* xr = (const float4*)(x + (size_t)(b * NC + c0 + j) * HW);
        float4 q0 = ntload4(xr + lane);
        float4 q1 = ntload4(xr + lane + 64);
        float4 q2 = ntload4(xr + lane + 128);
        float sum = dot4(q0, m0) + dot4(q1, m1) + dot4(q2, m2);
        float mm  = fmaxf(fmaxf(max4(q0), max4(q1)), max4(q2));
        if (lane < 4) {
            float4 q3 = ntload4(xr + lane + 192);
            sum += dot4(q3, m3);
            mm = fmaxf(mm, max4(q3));
        }
        if (lane == 0) sum += q0.x;   // reference's + x[b,c,0,0] term
        s[j] = sum; mx[j] = mm;
    }

    // ---- wave reductions: 8 sums, 8 maxes, 1 count ----
    for (int off = 32; off > 0; off >>= 1) {
        mc += __shfl_down(mc, off);
#pragma unroll
        for (int j = 0; j < 8; ++j) {
            s[j] += __shfl_down(s[j], off);
            mx[j] = fmaxf(mx[j], __shfl_down(mx[j], off));
        }
    }

    if (lane == 0) {
        const float inv = 1.0f / ((mc == 0.0f) ? 1.0f : mc);
#pragma unroll
        for (int j = 0; j < 8; ++j) {
            const int c = c0 + j;
            out[(size_t)b * (2 * NC) + c]      = s[j] * inv;
            out[(size_t)b * (2 * NC) + NC + c] = mx[j];
        }
    }
}

extern "C" void kernel_launch(void* const* d_in, const int* in_sizes, int n_in,
                              void* d_out, int out_size, void* d_ws, size_t ws_size,
                              hipStream_t stream) {
    const float* x  = (const float*)d_in[0];
    const void*  cc = d_in[1];
    float* out = (float*)d_out;
    pool_fused_kernel<<<dim3(NB * 16), dim3(256), 0, stream>>>(x, cc, out);
}